// Round 8
// baseline (50.805 us; speedup 1.0000x reference)
//
#include <hip/hip_runtime.h>

#define VOCAB 30522
#define D     768
#define NC    9
#define NROWS 16384          // 32*512
#define NB    256            // blocks (<= CU count; >=2 blocks/CU capacity -> co-resident)
#define TPB   512            // 8 waves
#define RPW   8              // rows per wave
#define RPB   64             // rows per block
#define SLICE 120            // 256*120 = 30720 >= VOCAB

typedef float v2f __attribute__((ext_vector_type(2)));

// ws layout (bytes):
//   [0,64)        barrier counter (zeroed by 64-B memset node each call)
//   [256, 65792)  means[NROWS] f32
//   [65792, ...)  ctxtab[NB*SLICE] f32 (123 KB)
#define WS_MEANS_OFF  256
#define WS_CTX_OFF    (WS_MEANS_OFF + NROWS * 4)

// ---------------------------------------------------------------------------
// Full-wave (64-lane) sum via DPP — pure VALU. Result valid in lane 63.
// ---------------------------------------------------------------------------
__device__ __forceinline__ float wave_reduce_add(float x) {
#define DPP_STEP(ctrl)                                                         \
    do {                                                                       \
        int t_ = __builtin_amdgcn_update_dpp(0, __float_as_int(x), (ctrl),     \
                                             0xf, 0xf, true);                  \
        x += __int_as_float(t_);                                               \
    } while (0)
    DPP_STEP(0x111); DPP_STEP(0x112); DPP_STEP(0x114); DPP_STEP(0x118);
    DPP_STEP(0x142); DPP_STEP(0x143);
#undef DPP_STEP
    return x;
}

// wsum2[c] = sum_{d>=768} W[d,c].  Waves 0..3; lane-63 writes to LDS dst.
__device__ __forceinline__ void compute_wsum2(const float* __restrict__ W,
                                              int lane, int wave, float* dst) {
    float s0 = 0.f, s1 = 0.f, s2 = 0.f;
    #pragma unroll
    for (int k = 0; k < 12; ++k) {
        const float* rw = W + (size_t)(D + lane + 64 * k) * NC;
        s0 += rw[wave];
        s1 += rw[wave + 4];
        if (wave == 0) s2 += rw[8];
    }
    s0 = wave_reduce_add(s0);
    s1 = wave_reduce_add(s1);
    s2 = wave_reduce_add(s2);
    if (lane == 63) {
        dst[wave]     = s0;
        dst[wave + 4] = s1;
        if (wave == 0) dst[8] = s2;
    }
}

__device__ __forceinline__ void fma4(v2f (&acc)[5], float4 v,
                                     const v2f (&wk)[4][5]) {
    const float vv[4] = {v.x, v.y, v.z, v.w};
    #pragma unroll
    for (int j = 0; j < 4; ++j) {
        const v2f b = {vv[j], vv[j]};
        #pragma unroll
        for (int p = 0; p < 5; ++p)
            acc[p] = __builtin_elementwise_fma(b, wk[j][p], acc[p]);
    }
}

// Device-scope barrier: release-add, spin (lane 0 only), acquire-fence.
// Counter is monotonically increasing within one call: targets NB, 2*NB.
__device__ __forceinline__ void dev_barrier(int* cnt, int target) {
    __syncthreads();   // all block stores retired (compiler drains vmcnt)
    if (threadIdx.x == 0) {
        __hip_atomic_fetch_add(cnt, 1, __ATOMIC_RELEASE,
                               __HIP_MEMORY_SCOPE_AGENT);   // wbl2 before add
        while (__hip_atomic_load(cnt, __ATOMIC_RELAXED,
                                 __HIP_MEMORY_SCOPE_AGENT) < target)
            __builtin_amdgcn_s_sleep(2);
        __builtin_amdgcn_fence(__ATOMIC_ACQUIRE, "agent");  // inv L2
    }
    __syncthreads();
}

// ---------------------------------------------------------------------------
// Single fused kernel (+ a 64-B memset node for the barrier counter).
// A: stream 64 rows/block (dots->LDS, means->global), per-block wsum2.
// bar1 | C: scan (ids,means), build vocab slice [bid*120,+120) -> ctxtab.
// bar2 | D: ctx gather for own rows, write out once (coalesced, no RMW).
// ---------------------------------------------------------------------------
__global__ __launch_bounds__(TPB) void fused_kernel(
    const float* __restrict__ h, const float* __restrict__ W,
    const int* __restrict__ ids, const float* __restrict__ bias,
    int* __restrict__ counter, float* __restrict__ means,
    float* __restrict__ ctxtab, float* __restrict__ out)
{
    __shared__ float s_dots[RPB * NC];   // [64 rows][9]
    __shared__ float s_sum[SLICE];
    __shared__ float s_cnt[SLICE];
    __shared__ float s_ctx[RPB];
    __shared__ float s_wsum2[NC];
    __shared__ float s_bias[NC];

    const int tid  = threadIdx.x;
    const int lane = tid & 63;
    const int wave = tid >> 6;           // 0..7
    const int bid  = blockIdx.x;
    const int base = bid * RPB + wave * RPW;

    // ---- Phase A: W fragment prologue (27 coalesced float4 per lane).
    v2f wf[3][4][5];
    #pragma unroll
    for (int k = 0; k < 3; ++k) {
        const float4* wp = (const float4*)W + (size_t)(lane + 64 * k) * 9;
        float w36[36];
        #pragma unroll
        for (int i = 0; i < 9; ++i) {
            float4 v = wp[i];
            w36[4*i+0] = v.x; w36[4*i+1] = v.y; w36[4*i+2] = v.z; w36[4*i+3] = v.w;
        }
        #pragma unroll
        for (int j = 0; j < 4; ++j) {
            #pragma unroll
            for (int p = 0; p < 4; ++p)
                wf[k][j][p] = (v2f){w36[j*9 + 2*p], w36[j*9 + 2*p + 1]};
            wf[k][j][4] = (v2f){w36[j*9 + 8], 1.0f};
        }
    }

    const float4* hb = (const float4*)h + (size_t)base * (D / 4) + lane;
#define LDROW(rr, V0, V1, V2)                                                  \
    do { const float4* hp_ = hb + (size_t)(rr) * (D / 4);                      \
         V0 = hp_[0]; V1 = hp_[64]; V2 = hp_[128]; } while (0)

    float4 A0, A1, A2, B0, B1, B2;
    LDROW(0, A0, A1, A2);
    LDROW(1, B0, B1, B2);

    #pragma unroll
    for (int rp = 0; rp < RPW / 2; ++rp) {
        float4 N0, N1, N2, M0, M1, M2;
        if (rp < RPW / 2 - 1) {
            LDROW(2 * rp + 2, N0, N1, N2);
            LDROW(2 * rp + 3, M0, M1, M2);
        }
        const int rA = base + 2 * rp, rB = rA + 1;

        v2f accA[5], accB[5];
        #pragma unroll
        for (int p = 0; p < 5; ++p) {
            accA[p] = (v2f){0.f, 0.f};
            accB[p] = (v2f){0.f, 0.f};
        }
        fma4(accA, A0, wf[0]); fma4(accA, A1, wf[1]); fma4(accA, A2, wf[2]);
        fma4(accB, B0, wf[0]); fma4(accB, B1, wf[1]); fma4(accB, B2, wf[2]);

        float ra[10] = {accA[0].x, accA[0].y, accA[1].x, accA[1].y, accA[2].x,
                        accA[2].y, accA[3].x, accA[3].y, accA[4].x, accA[4].y};
        float rb[10] = {accB[0].x, accB[0].y, accB[1].x, accB[1].y, accB[2].x,
                        accB[2].y, accB[3].x, accB[3].y, accB[4].x, accB[4].y};
        #pragma unroll
        for (int t = 0; t < 10; ++t) {
            ra[t] = wave_reduce_add(ra[t]);
            rb[t] = wave_reduce_add(rb[t]);
        }

        if (lane == 63) {
            const int lA = wave * RPW + 2 * rp;      // local row in block
            #pragma unroll
            for (int c = 0; c < 9; ++c) {
                s_dots[lA * NC + c]       = ra[c];
                s_dots[(lA + 1) * NC + c] = rb[c];
            }
            means[rA] = ra[9] * (1.f / 768.f);       // plain store; bar1 release flushes
            means[rB] = rb[9] * (1.f / 768.f);
        }

        if (rp < RPW / 2 - 1) {
            A0 = N0; A1 = N1; A2 = N2;
            B0 = M0; B1 = M1; B2 = M2;
        }
    }
#undef LDROW

    if (wave < 4) compute_wsum2(W, lane, wave, s_wsum2);
    if (tid < SLICE) { s_sum[tid] = 0.f; s_cnt[tid] = 0.f; }
    if (tid < NC)    s_bias[tid] = bias[tid];

    // ---- Barrier 1: all means visible device-wide.
    dev_barrier(counter, NB);

    // ---- Phase C: build this block's vocab slice from all (id, mean) pairs.
    const int lo = bid * SLICE;
    const int4*   ids4   = (const int4*)ids;
    const float4* means4 = (const float4*)means;
    #pragma unroll
    for (int k = 0; k < NROWS / 4 / TPB; ++k) {      // 8 iterations
        const int q = tid + k * TPB;
        const int4   i4 = ids4[q];
        const float4 m4 = means4[q];
        const int k0 = i4.x - lo, k1 = i4.y - lo, k2 = i4.z - lo, k3 = i4.w - lo;
        if ((unsigned)k0 < (unsigned)SLICE) { atomicAdd(&s_sum[k0], m4.x); atomicAdd(&s_cnt[k0], 1.f); }
        if ((unsigned)k1 < (unsigned)SLICE) { atomicAdd(&s_sum[k1], m4.y); atomicAdd(&s_cnt[k1], 1.f); }
        if ((unsigned)k2 < (unsigned)SLICE) { atomicAdd(&s_sum[k2], m4.z); atomicAdd(&s_cnt[k2], 1.f); }
        if ((unsigned)k3 < (unsigned)SLICE) { atomicAdd(&s_sum[k3], m4.w); atomicAdd(&s_cnt[k3], 1.f); }
    }
    __syncthreads();
    if (tid < SLICE)
        ctxtab[lo + tid] = s_sum[tid] / fmaxf(s_cnt[tid], 1.f);  // bar2 flushes

    // ---- Barrier 2: full ctxtab visible device-wide.
    dev_barrier(counter, 2 * NB);

    // ---- Phase D: gather ctx for own rows; write out once, coalesced.
    if (tid < RPB) s_ctx[tid] = ctxtab[ids[bid * RPB + tid]];
    __syncthreads();

    float* ob = out + (size_t)bid * RPB * NC;
    for (int t = tid; t < RPB * NC; t += TPB) {
        const int r = t / NC, c = t - r * NC;
        ob[t] = s_dots[t] + fmaf(s_ctx[r], s_wsum2[c], s_bias[c]);
    }
}

extern "C" void kernel_launch(void* const* d_in, const int* in_sizes, int n_in,
                              void* d_out, int out_size, void* d_ws, size_t ws_size,
                              hipStream_t stream) {
    const int*   ids = (const int*)  d_in[0];  // [32,512] int32
    const float* h   = (const float*)d_in[1];  // [32,512,768] f32
    const float* W   = (const float*)d_in[2];  // [1536,9] f32
    const float* b   = (const float*)d_in[3];  // [9] f32
    float* out = (float*)d_out;                // [32,512,9] f32

    int*   counter = (int*)d_ws;
    float* means   = (float*)((char*)d_ws + WS_MEANS_OFF);
    float* ctxtab  = (float*)((char*)d_ws + WS_CTX_OFF);

    hipMemsetAsync(d_ws, 0, 64, stream);       // zero barrier counter (64 B)
    fused_kernel<<<NB, TPB, 0, stream>>>(h, W, ids, b, counter, means, ctxtab, out);
}